// Round 1
// baseline (4543.383 us; speedup 1.0000x reference)
//
#include <hip/hip_runtime.h>
#include <hip/hip_bf16.h>
#include <cstddef>

#define B   2
#define S   1024
#define PP  1024          // start_pos
#define CTX 2048
#define E   2048
#define H   32
#define KVH 8
#define HD  64
#define GQ  4             // H / KVH
#define TQ  4             // queries per attention block

// ---------------------------------------------------------------------------
// Tiled fp32 GEMM, C[M,N] = A[M,K] @ B[N,K]^T   (both row-major along K)
// ---------------------------------------------------------------------------
template<int BM, int BN, int BK, int TM, int TN>
__global__ __launch_bounds__(256) void gemm_bt(const float* __restrict__ A,
                                               const float* __restrict__ Bw,
                                               float* __restrict__ C,
                                               int M, int N, int K) {
  __shared__ float As[BK][BM + 4];
  __shared__ float Bs[BK][BN + 4];
  const int tid = threadIdx.x;
  const int m0 = blockIdx.y * BM;
  const int n0 = blockIdx.x * BN;
  // loader: BM*BK floats per tile, 256 threads, one float4 each
  const int arow = tid / (BK / 4);
  const int acol = (tid % (BK / 4)) * 4;
  const int tx = tid % (BN / TN);
  const int ty = tid / (BN / TN);
  float acc[TM][TN] = {};
  for (int k0 = 0; k0 < K; k0 += BK) {
    float4 av = *(const float4*)&A[(size_t)(m0 + arow) * K + k0 + acol];
    float4 bv = *(const float4*)&Bw[(size_t)(n0 + arow) * K + k0 + acol];
    __syncthreads();
    As[acol + 0][arow] = av.x; As[acol + 1][arow] = av.y;
    As[acol + 2][arow] = av.z; As[acol + 3][arow] = av.w;
    Bs[acol + 0][arow] = bv.x; Bs[acol + 1][arow] = bv.y;
    Bs[acol + 2][arow] = bv.z; Bs[acol + 3][arow] = bv.w;
    __syncthreads();
#pragma unroll
    for (int kk = 0; kk < BK; kk++) {
      float a[TM], b[TN];
#pragma unroll
      for (int i = 0; i < TM; i += 4) *(float4*)&a[i] = *(const float4*)&As[kk][ty * TM + i];
#pragma unroll
      for (int j = 0; j < TN; j += 4) *(float4*)&b[j] = *(const float4*)&Bs[kk][tx * TN + j];
#pragma unroll
      for (int i = 0; i < TM; i++)
#pragma unroll
        for (int j = 0; j < TN; j++) acc[i][j] += a[i] * b[j];
    }
  }
#pragma unroll
  for (int i = 0; i < TM; i++) {
#pragma unroll
    for (int j = 0; j < TN; j += 4) {
      float4 o = make_float4(acc[i][j], acc[i][j + 1], acc[i][j + 2], acc[i][j + 3]);
      *(float4*)&C[(size_t)(m0 + ty * TM + i) * N + n0 + tx * TN + j] = o;
    }
  }
}

// ---------------------------------------------------------------------------
// RoPE on q, in place. q layout (B,S,H,HD). cos/sin (B,S,HD), halves equal.
// ---------------------------------------------------------------------------
__global__ __launch_bounds__(256) void rope_q(float* __restrict__ q,
                                              const float* __restrict__ cosb,
                                              const float* __restrict__ sinb) {
  int idx = blockIdx.x * 256 + threadIdx.x;   // over B*S*H*32 = 2^21
  int d = idx & 31;
  int h = (idx >> 5) & (H - 1);
  int s = (idx >> 10) & (S - 1);
  int b = idx >> 20;
  size_t row = (size_t)b * S + s;
  float c = cosb[row * HD + d];
  float sn = sinb[row * HD + d];
  float* qp = q + ((row * H) + h) * HD;
  float q1 = qp[d], q2 = qp[d + 32];
  qp[d] = q1 * c - q2 * sn;
  qp[d + 32] = q2 * c + q1 * sn;
}

// ---------------------------------------------------------------------------
// RoPE on k_tmp (B,S,KVH,HD) + scatter into keys (B,KVH,CTX,HD) at pos PP+s;
// also scatter v_tmp into vals.
// ---------------------------------------------------------------------------
__global__ __launch_bounds__(256) void rope_kv(const float* __restrict__ kt,
                                               const float* __restrict__ vt,
                                               const float* __restrict__ cosb,
                                               const float* __restrict__ sinb,
                                               float* __restrict__ keys,
                                               float* __restrict__ vals) {
  int idx = blockIdx.x * 256 + threadIdx.x;   // over B*S*KVH*32 = 2^19
  int d = idx & 31;
  int kv = (idx >> 5) & (KVH - 1);
  int s = (idx >> 8) & (S - 1);
  int b = idx >> 18;
  size_t row = (size_t)b * S + s;
  float c = cosb[row * HD + d];
  float sn = sinb[row * HD + d];
  const float* kp = kt + (row * KVH + kv) * HD;
  const float* vp = vt + (row * KVH + kv) * HD;
  size_t drow = (((size_t)b * KVH + kv) * CTX + PP + s) * HD;
  float k1 = kp[d], k2 = kp[d + 32];
  keys[drow + d] = k1 * c - k2 * sn;
  keys[drow + d + 32] = k2 * c + k1 * sn;
  vals[drow + d] = vp[d];
  vals[drow + d + 32] = vp[d + 32];
}

// ---------------------------------------------------------------------------
// Copy cache_k/cache_v positions [0,PP) into keys/vals (same layout).
// ---------------------------------------------------------------------------
__global__ __launch_bounds__(256) void copy_cache(const float4* __restrict__ ck,
                                                  const float4* __restrict__ cv,
                                                  float4* __restrict__ keys,
                                                  float4* __restrict__ vals) {
  int idx = blockIdx.x * 256 + threadIdx.x;   // over B*KVH*PP*HD/4 = 262144
  const int per = PP * HD / 4;                 // 16384
  int bkv = idx / per;
  int rem = idx % per;
  size_t off = (size_t)bkv * (CTX * HD / 4) + rem;
  keys[off] = ck[off];
  vals[off] = cv[off];
}

// ---------------------------------------------------------------------------
// Attention: one block handles (b, h, sq0..sq0+TQ-1). Full-score softmax in
// LDS. Writes result IN PLACE into the q buffer (block-local rows only).
// ---------------------------------------------------------------------------
__global__ __launch_bounds__(256) void attn_kernel(const float* __restrict__ q,
                                                   const float* __restrict__ keys,
                                                   const float* __restrict__ vals,
                                                   float* __restrict__ attn) {
  __shared__ float p[TQ][CTX];        // 32 KB
  __shared__ float smax[TQ], ssum[TQ];
  __shared__ float osum[8][TQ][HD];   // 8 KB

  const int blk = blockIdx.x;               // over B*H*(S/TQ)
  const int sq0 = (blk % (S / TQ)) * TQ;
  const int h   = (blk / (S / TQ)) % H;
  const int b   = blk / ((S / TQ) * H);
  const int kv  = h / GQ;
  const int kmaxmax = PP + sq0 + TQ;        // exclusive upper bound on key pos

  const int tid = threadIdx.x;
  const int qi = tid >> 6;                  // 0..3, one query per wave
  const int kl = tid & 63;

  // q vector for this thread's query, in registers
  float4 qreg[16];
  const float* qp = q + (((size_t)b * S + sq0 + qi) * H + h) * HD;
#pragma unroll
  for (int i = 0; i < 16; i++) qreg[i] = ((const float4*)qp)[i];

  const float* kbase = keys + ((size_t)b * KVH + kv) * (size_t)CTX * HD;
  const float* vbase = vals + ((size_t)b * KVH + kv) * (size_t)CTX * HD;

  // ---- QK^T ----
  float lmax = -1e30f;
  for (int t = kl; t < kmaxmax; t += 64) {
    const float4* kp = (const float4*)(kbase + (size_t)t * HD);
    float dot = 0.f;
#pragma unroll
    for (int i = 0; i < 16; i++) {
      float4 k4 = kp[i];
      dot += qreg[i].x * k4.x + qreg[i].y * k4.y + qreg[i].z * k4.z + qreg[i].w * k4.w;
    }
    float sc = dot * 0.125f;                 // 1/sqrt(64)
    if (t > PP + sq0 + qi) sc = -1e30f;      // causal mask (== ref's -1e9 add: exp underflows to 0)
    p[qi][t] = sc;
    lmax = fmaxf(lmax, sc);
  }
#pragma unroll
  for (int m = 32; m >= 1; m >>= 1) lmax = fmaxf(lmax, __shfl_xor(lmax, m));
  if (kl == 0) smax[qi] = lmax;
  __syncthreads();

  // ---- exp + sum ----
  const float mx = smax[qi];
  float lsum = 0.f;
  for (int t = kl; t < kmaxmax; t += 64) {
    float e = __expf(p[qi][t] - mx);
    p[qi][t] = e;
    lsum += e;
  }
#pragma unroll
  for (int m = 32; m >= 1; m >>= 1) lsum += __shfl_xor(lsum, m);
  if (kl == 0) ssum[qi] = lsum;
  __syncthreads();

  // ---- P @ V ----
  const int tq = kl >> 3;                   // 0..7 key phase
  const int dd = (kl & 7) * 8;              // 8-float chunk of HD
  float o[8] = {};
  for (int t = tq; t < kmaxmax; t += 8) {
    float pw = p[qi][t];
    const float4* vp = (const float4*)(vbase + (size_t)t * HD + dd);
    float4 v0 = vp[0], v1 = vp[1];
    o[0] += pw * v0.x; o[1] += pw * v0.y; o[2] += pw * v0.z; o[3] += pw * v0.w;
    o[4] += pw * v1.x; o[5] += pw * v1.y; o[6] += pw * v1.z; o[7] += pw * v1.w;
  }
#pragma unroll
  for (int i = 0; i < 8; i++) osum[tq][qi][dd + i] = o[i];
  __syncthreads();

  // ---- reduce 8 key-phases, normalize, write (b, sq, h, :) ----
  {
    int oqi = tid >> 6;
    int od = tid & 63;
    float r = 0.f;
#pragma unroll
    for (int t8 = 0; t8 < 8; t8++) r += osum[t8][oqi][od];
    r /= ssum[oqi];
    attn[(((size_t)b * S + sq0 + oqi) * H + h) * HD + od] = r;
  }
}

// ---------------------------------------------------------------------------
extern "C" void kernel_launch(void* const* d_in, const int* in_sizes, int n_in,
                              void* d_out, int out_size, void* d_ws, size_t ws_size,
                              hipStream_t stream) {
  const float* x       = (const float*)d_in[0];
  const float* cosb    = (const float*)d_in[1];
  const float* sinb    = (const float*)d_in[2];
  // d_in[3] mask: causal with -1e9, computed analytically in attn_kernel
  const float* cache_k = (const float*)d_in[4];
  const float* cache_v = (const float*)d_in[5];
  const float* Wq      = (const float*)d_in[6];
  const float* Wk      = (const float*)d_in[7];
  const float* Wv      = (const float*)d_in[8];
  const float* Wo      = (const float*)d_in[9];
  float* out = (float*)d_out;

  float* ws    = (float*)d_ws;
  float* q_buf = ws;                                   // B*S*E      = 4194304
  float* k_tmp = q_buf + (size_t)B * S * E;            // B*S*KVH*HD = 1048576
  float* v_tmp = k_tmp + (size_t)B * S * KVH * HD;
  float* keys  = v_tmp + (size_t)B * S * KVH * HD;     // B*KVH*CTX*HD = 2097152
  float* vals  = keys + (size_t)B * KVH * CTX * HD;    // total 10.5M floats = 42 MB

  dim3 blk(256);

  // Q/K/V projections
  gemm_bt<128, 128, 8, 8, 8><<<dim3(E / 128, (B * S) / 128), blk, 0, stream>>>(x, Wq, q_buf, B * S, E, E);
  gemm_bt<64, 64, 16, 4, 4><<<dim3((KVH * HD) / 64, (B * S) / 64), blk, 0, stream>>>(x, Wk, k_tmp, B * S, KVH * HD, E);
  gemm_bt<64, 64, 16, 4, 4><<<dim3((KVH * HD) / 64, (B * S) / 64), blk, 0, stream>>>(x, Wv, v_tmp, B * S, KVH * HD, E);

  // RoPE + KV cache assembly
  rope_q<<<(B * S * H * 32) / 256, blk, 0, stream>>>(q_buf, cosb, sinb);
  rope_kv<<<(B * S * KVH * 32) / 256, blk, 0, stream>>>(k_tmp, v_tmp, cosb, sinb, keys, vals);
  copy_cache<<<(B * KVH * PP * HD / 4) / 256, blk, 0, stream>>>(
      (const float4*)cache_k, (const float4*)cache_v, (float4*)keys, (float4*)vals);

  // Attention (writes attn output in place into q_buf, layout (B,S,H,HD)=(B,S,E))
  attn_kernel<<<B * H * (S / TQ), blk, 0, stream>>>(q_buf, keys, vals, q_buf);

  // Output projection
  gemm_bt<128, 128, 8, 8, 8><<<dim3(E / 128, (B * S) / 128), blk, 0, stream>>>(q_buf, Wo, out, B * S, E, E);
}

// Round 2
// 1031.005 us; speedup vs baseline: 4.4068x; 4.4068x over previous
//
#include <hip/hip_runtime.h>
#include <hip/hip_bf16.h>
#include <cstddef>

#define B   2
#define S   1024
#define PP  1024          // start_pos
#define CTX 2048
#define E   2048
#define H   32
#define KVH 8
#define HD  64
#define GQ  4             // H / KVH

typedef short s4v  __attribute__((ext_vector_type(4)));
typedef short s8v  __attribute__((ext_vector_type(8)));
typedef float f4v  __attribute__((ext_vector_type(4)));

__device__ inline short f2bf(float f) {   // RNE f32 -> bf16
  union { float f; unsigned u; } v; v.f = f;
  unsigned r = v.u + 0x7fffu + ((v.u >> 16) & 1u);
  return (short)(r >> 16);
}

// ---------------------------------------------------------------------------
// Tiled fp32 GEMM, C[M,N] = A[M,K] @ B[N,K]^T   (both row-major along K)
// ---------------------------------------------------------------------------
template<int BM, int BN, int BK, int TM, int TN>
__global__ __launch_bounds__(256) void gemm_bt(const float* __restrict__ A,
                                               const float* __restrict__ Bw,
                                               float* __restrict__ C,
                                               int M, int N, int K) {
  __shared__ float As[BK][BM + 4];
  __shared__ float Bs[BK][BN + 4];
  const int tid = threadIdx.x;
  const int m0 = blockIdx.y * BM;
  const int n0 = blockIdx.x * BN;
  const int arow = tid / (BK / 4);
  const int acol = (tid % (BK / 4)) * 4;
  const int tx = tid % (BN / TN);
  const int ty = tid / (BN / TN);
  float acc[TM][TN] = {};
  for (int k0 = 0; k0 < K; k0 += BK) {
    float4 av = *(const float4*)&A[(size_t)(m0 + arow) * K + k0 + acol];
    float4 bv = *(const float4*)&Bw[(size_t)(n0 + arow) * K + k0 + acol];
    __syncthreads();
    As[acol + 0][arow] = av.x; As[acol + 1][arow] = av.y;
    As[acol + 2][arow] = av.z; As[acol + 3][arow] = av.w;
    Bs[acol + 0][arow] = bv.x; Bs[acol + 1][arow] = bv.y;
    Bs[acol + 2][arow] = bv.z; Bs[acol + 3][arow] = bv.w;
    __syncthreads();
#pragma unroll
    for (int kk = 0; kk < BK; kk++) {
      float a[TM], b[TN];
#pragma unroll
      for (int i = 0; i < TM; i += 4) *(float4*)&a[i] = *(const float4*)&As[kk][ty * TM + i];
#pragma unroll
      for (int j = 0; j < TN; j += 4) *(float4*)&b[j] = *(const float4*)&Bs[kk][tx * TN + j];
#pragma unroll
      for (int i = 0; i < TM; i++)
#pragma unroll
        for (int j = 0; j < TN; j++) acc[i][j] += a[i] * b[j];
    }
  }
#pragma unroll
  for (int i = 0; i < TM; i++) {
#pragma unroll
    for (int j = 0; j < TN; j += 4) {
      float4 o = make_float4(acc[i][j], acc[i][j + 1], acc[i][j + 2], acc[i][j + 3]);
      *(float4*)&C[(size_t)(m0 + ty * TM + i) * N + n0 + tx * TN + j] = o;
    }
  }
}

// ---------------------------------------------------------------------------
// RoPE on q, in place. q layout (B,S,H,HD). cos/sin (B,S,HD), halves equal.
// ---------------------------------------------------------------------------
__global__ __launch_bounds__(256) void rope_q(float* __restrict__ q,
                                              const float* __restrict__ cosb,
                                              const float* __restrict__ sinb) {
  int idx = blockIdx.x * 256 + threadIdx.x;
  int d = idx & 31;
  int h = (idx >> 5) & (H - 1);
  int s = (idx >> 10) & (S - 1);
  int b = idx >> 20;
  size_t row = (size_t)b * S + s;
  float c = cosb[row * HD + d];
  float sn = sinb[row * HD + d];
  float* qp = q + ((row * H) + h) * HD;
  float q1 = qp[d], q2 = qp[d + 32];
  qp[d] = q1 * c - q2 * sn;
  qp[d + 32] = q2 * c + q1 * sn;
}

__global__ __launch_bounds__(256) void rope_kv(const float* __restrict__ kt,
                                               const float* __restrict__ vt,
                                               const float* __restrict__ cosb,
                                               const float* __restrict__ sinb,
                                               float* __restrict__ keys,
                                               float* __restrict__ vals) {
  int idx = blockIdx.x * 256 + threadIdx.x;
  int d = idx & 31;
  int kv = (idx >> 5) & (KVH - 1);
  int s = (idx >> 8) & (S - 1);
  int b = idx >> 18;
  size_t row = (size_t)b * S + s;
  float c = cosb[row * HD + d];
  float sn = sinb[row * HD + d];
  const float* kp = kt + (row * KVH + kv) * HD;
  const float* vp = vt + (row * KVH + kv) * HD;
  size_t drow = (((size_t)b * KVH + kv) * CTX + PP + s) * HD;
  float k1 = kp[d], k2 = kp[d + 32];
  keys[drow + d] = k1 * c - k2 * sn;
  keys[drow + d + 32] = k2 * c + k1 * sn;
  vals[drow + d] = vp[d];
  vals[drow + d + 32] = vp[d + 32];
}

__global__ __launch_bounds__(256) void copy_cache(const float4* __restrict__ ck,
                                                  const float4* __restrict__ cv,
                                                  float4* __restrict__ keys,
                                                  float4* __restrict__ vals) {
  int idx = blockIdx.x * 256 + threadIdx.x;
  const int per = PP * HD / 4;
  int bkv = idx / per;
  int rem = idx % per;
  size_t off = (size_t)bkv * (CTX * HD / 4) + rem;
  keys[off] = ck[off];
  vals[off] = cv[off];
}

// ---------------------------------------------------------------------------
// MFMA bf16 flash attention.
// Block: 4 waves, each wave owns 16 queries of one (b,h); 64 queries/block.
// Scores computed TRANSPOSED (S^T = K_tile @ Q^T) so the exponentiated P is
// one LDS b64 write away from the PV A-operand layout.
// C/D layout (verified): col = lane&15, row = (lane>>4)*4 + reg.
// A/B k-slot maps only need A/B consistency (contraction is k-permutation
// invariant), so frags are read as 8 consecutive bf16 along k.
// ---------------------------------------------------------------------------
__global__ __launch_bounds__(256) void attn_mfma(const float* __restrict__ q,
                                                 const float* __restrict__ keys,
                                                 const float* __restrict__ vals,
                                                 float* __restrict__ attn) {
  __shared__ short Ks[64][68];     // K tile,  row-major [key][dim], bf16
  __shared__ short VTs[64][68];    // V tile transposed [dim][key], bf16
  __shared__ short Pb[4][16][68];  // per-wave P [query][key], bf16

  const int sblk = 15 - (blockIdx.x & 15);     // long blocks first
  const int h    = (blockIdx.x >> 4) & (H - 1);
  const int b    = blockIdx.x >> 9;
  const int kv   = h >> 2;                     // h / GQ
  const int sq0  = sblk * 64;
  const int kend = PP + sq0 + 64;              // exclusive key bound (mult of 64)

  const int tid  = threadIdx.x;
  const int w    = tid >> 6;
  const int lane = tid & 63;
  const int n    = lane & 15;                  // query-col / frag row index
  const int g    = lane >> 4;                  // k-group

  const float* kbase = keys + ((size_t)b * KVH + kv) * CTX * HD;
  const float* vbase = vals + ((size_t)b * KVH + kv) * CTX * HD;

  // ---- load Q fragments (16 queries x 64 dims), fold 1/sqrt(HD) ----
  union { s4v h4[2]; s8v v; } qlo, qhi;
  {
    const float* qrow = q + (((size_t)b * S + sq0 + w * 16 + n) * H + h) * HD;
    float4 f0 = *(const float4*)&qrow[g * 8];
    float4 f1 = *(const float4*)&qrow[g * 8 + 4];
    float4 f2 = *(const float4*)&qrow[32 + g * 8];
    float4 f3 = *(const float4*)&qrow[32 + g * 8 + 4];
    s4v a, c;
    a[0]=f2bf(f0.x*0.125f); a[1]=f2bf(f0.y*0.125f); a[2]=f2bf(f0.z*0.125f); a[3]=f2bf(f0.w*0.125f);
    qlo.h4[0]=a;
    a[0]=f2bf(f1.x*0.125f); a[1]=f2bf(f1.y*0.125f); a[2]=f2bf(f1.z*0.125f); a[3]=f2bf(f1.w*0.125f);
    qlo.h4[1]=a;
    c[0]=f2bf(f2.x*0.125f); c[1]=f2bf(f2.y*0.125f); c[2]=f2bf(f2.z*0.125f); c[3]=f2bf(f2.w*0.125f);
    qhi.h4[0]=c;
    c[0]=f2bf(f3.x*0.125f); c[1]=f2bf(f3.y*0.125f); c[2]=f2bf(f3.z*0.125f); c[3]=f2bf(f3.w*0.125f);
    qhi.h4[1]=c;
  }

  f4v O0 = {0,0,0,0}, O1 = {0,0,0,0}, O2 = {0,0,0,0}, O3 = {0,0,0,0};
  float m = -3e38f, l = 0.f;
  const int qp     = PP + sq0 + w * 16 + n;    // this lane's query position
  const int qmax_w = PP + sq0 + w * 16 + 15;   // wave's max query position
  const int qmin_w = PP + sq0 + w * 16;

  for (int k0 = 0; k0 < kend; k0 += 64) {
    __syncthreads();   // previous tile's readers done
    // ---- stage K tile (row-major bf16) ----
    {
      int row = tid >> 2, c4 = tid & 3;
      const float* kr = kbase + (size_t)(k0 + row) * HD;
#pragma unroll
      for (int i = 0; i < 4; i++) {
        float4 f = *(const float4*)&kr[(c4 + 4 * i) * 4];
        s4v p; p[0]=f2bf(f.x); p[1]=f2bf(f.y); p[2]=f2bf(f.z); p[3]=f2bf(f.w);
        *(s4v*)&Ks[row][(c4 + 4 * i) * 4] = p;
      }
      // ---- stage V^T tile (4x4 register transpose) ----
      int dq = tid & 15, kb = tid >> 4;
      float4 vv[4];
#pragma unroll
      for (int i = 0; i < 4; i++)
        vv[i] = *(const float4*)&vbase[(size_t)(k0 + kb * 4 + i) * HD + dq * 4];
#pragma unroll
      for (int j = 0; j < 4; j++) {
        s4v p;
        p[0]=f2bf(((const float*)&vv[0])[j]); p[1]=f2bf(((const float*)&vv[1])[j]);
        p[2]=f2bf(((const float*)&vv[2])[j]); p[3]=f2bf(((const float*)&vv[3])[j]);
        *(s4v*)&VTs[dq * 4 + j][kb * 4] = p;
      }
    }
    __syncthreads();

    if (k0 > qmax_w) continue;   // wave-uniform: fully masked step

    // ---- S^T = K_tile @ Q^T : 4 subtiles of 16 keys ----
    f4v sc[4];
#pragma unroll
    for (int st = 0; st < 4; st++) {
      union { s4v h4[2]; s8v v; } alo, ahi;
      alo.h4[0] = *(const s4v*)&Ks[st * 16 + n][g * 8];
      alo.h4[1] = *(const s4v*)&Ks[st * 16 + n][g * 8 + 4];
      ahi.h4[0] = *(const s4v*)&Ks[st * 16 + n][32 + g * 8];
      ahi.h4[1] = *(const s4v*)&Ks[st * 16 + n][32 + g * 8 + 4];
      f4v z = {0.f, 0.f, 0.f, 0.f};
      z = __builtin_amdgcn_mfma_f32_16x16x32_bf16(alo.v, qlo.v, z, 0, 0, 0);
      sc[st] = __builtin_amdgcn_mfma_f32_16x16x32_bf16(ahi.v, qhi.v, z, 0, 0, 0);
    }

    // ---- causal mask (only near the diagonal) ----
    if (k0 + 63 > qmin_w) {
#pragma unroll
      for (int st = 0; st < 4; st++)
#pragma unroll
        for (int r = 0; r < 4; r++) {
          int kpos = k0 + st * 16 + g * 4 + r;
          if (kpos > qp) sc[st][r] = -3e38f;
        }
    }

    // ---- online softmax (per query = col n) ----
    float ml = sc[0][0];
#pragma unroll
    for (int st = 0; st < 4; st++)
#pragma unroll
      for (int r = 0; r < 4; r++) ml = fmaxf(ml, sc[st][r]);
    ml = fmaxf(ml, __shfl_xor(ml, 16));
    ml = fmaxf(ml, __shfl_xor(ml, 32));
    float mn = fmaxf(m, ml);
    float alpha = __expf(m - mn);
    m = mn;
    float ls = 0.f;
#pragma unroll
    for (int st = 0; st < 4; st++) {
      s4v pw;
#pragma unroll
      for (int r = 0; r < 4; r++) {
        float e = __expf(sc[st][r] - m);
        ls += e;
        pw[r] = f2bf(e);
      }
      *(s4v*)&Pb[w][n][st * 16 + g * 4] = pw;   // P[query][key]
    }
    ls += __shfl_xor(ls, 16);
    ls += __shfl_xor(ls, 32);
    l = l * alpha + ls;

    // ---- rescale O (rows are queries g*4+r; alpha lives at lane q) ----
#pragma unroll
    for (int r = 0; r < 4; r++) {
      float ar = __shfl(alpha, g * 4 + r, 64);
      O0[r] *= ar; O1[r] *= ar; O2[r] *= ar; O3[r] *= ar;
    }

    // ---- O += P @ V  (two K=32 halves x four 16-wide d chunks) ----
#pragma unroll
    for (int kh = 0; kh < 2; kh++) {
      union { s4v h4[2]; s8v v; } pa;
      pa.h4[0] = *(const s4v*)&Pb[w][n][kh * 32 + g * 8];
      pa.h4[1] = *(const s4v*)&Pb[w][n][kh * 32 + g * 8 + 4];
      union { s4v h4[2]; s8v v; } vb;
      vb.h4[0] = *(const s4v*)&VTs[0 * 16 + n][kh * 32 + g * 8];
      vb.h4[1] = *(const s4v*)&VTs[0 * 16 + n][kh * 32 + g * 8 + 4];
      O0 = __builtin_amdgcn_mfma_f32_16x16x32_bf16(pa.v, vb.v, O0, 0, 0, 0);
      vb.h4[0] = *(const s4v*)&VTs[1 * 16 + n][kh * 32 + g * 8];
      vb.h4[1] = *(const s4v*)&VTs[1 * 16 + n][kh * 32 + g * 8 + 4];
      O1 = __builtin_amdgcn_mfma_f32_16x16x32_bf16(pa.v, vb.v, O1, 0, 0, 0);
      vb.h4[0] = *(const s4v*)&VTs[2 * 16 + n][kh * 32 + g * 8];
      vb.h4[1] = *(const s4v*)&VTs[2 * 16 + n][kh * 32 + g * 8 + 4];
      O2 = __builtin_amdgcn_mfma_f32_16x16x32_bf16(pa.v, vb.v, O2, 0, 0, 0);
      vb.h4[0] = *(const s4v*)&VTs[3 * 16 + n][kh * 32 + g * 8];
      vb.h4[1] = *(const s4v*)&VTs[3 * 16 + n][kh * 32 + g * 8 + 4];
      O3 = __builtin_amdgcn_mfma_f32_16x16x32_bf16(pa.v, vb.v, O3, 0, 0, 0);
    }
  }

  // ---- epilogue: normalize and store (rows = queries g*4+r) ----
#pragma unroll
  for (int r = 0; r < 4; r++) {
    float rl = 1.f / __shfl(l, g * 4 + r, 64);
    float* orow = attn + (((size_t)b * S + sq0 + w * 16 + g * 4 + r) * H + h) * HD + n;
    orow[0]  = O0[r] * rl;
    orow[16] = O1[r] * rl;
    orow[32] = O2[r] * rl;
    orow[48] = O3[r] * rl;
  }
}

// ---------------------------------------------------------------------------
extern "C" void kernel_launch(void* const* d_in, const int* in_sizes, int n_in,
                              void* d_out, int out_size, void* d_ws, size_t ws_size,
                              hipStream_t stream) {
  const float* x       = (const float*)d_in[0];
  const float* cosb    = (const float*)d_in[1];
  const float* sinb    = (const float*)d_in[2];
  const float* cache_k = (const float*)d_in[4];
  const float* cache_v = (const float*)d_in[5];
  const float* Wq      = (const float*)d_in[6];
  const float* Wk      = (const float*)d_in[7];
  const float* Wv      = (const float*)d_in[8];
  const float* Wo      = (const float*)d_in[9];
  float* out = (float*)d_out;

  float* ws    = (float*)d_ws;
  float* q_buf = ws;
  float* k_tmp = q_buf + (size_t)B * S * E;
  float* v_tmp = k_tmp + (size_t)B * S * KVH * HD;
  float* keys  = v_tmp + (size_t)B * S * KVH * HD;
  float* vals  = keys + (size_t)B * KVH * CTX * HD;

  dim3 blk(256);

  gemm_bt<128, 128, 8, 8, 8><<<dim3(E / 128, (B * S) / 128), blk, 0, stream>>>(x, Wq, q_buf, B * S, E, E);
  gemm_bt<64, 64, 16, 4, 4><<<dim3((KVH * HD) / 64, (B * S) / 64), blk, 0, stream>>>(x, Wk, k_tmp, B * S, KVH * HD, E);
  gemm_bt<64, 64, 16, 4, 4><<<dim3((KVH * HD) / 64, (B * S) / 64), blk, 0, stream>>>(x, Wv, v_tmp, B * S, KVH * HD, E);

  rope_q<<<(B * S * H * 32) / 256, blk, 0, stream>>>(q_buf, cosb, sinb);
  rope_kv<<<(B * S * KVH * 32) / 256, blk, 0, stream>>>(k_tmp, v_tmp, cosb, sinb, keys, vals);
  copy_cache<<<(B * KVH * PP * HD / 4) / 256, blk, 0, stream>>>(
      (const float4*)cache_k, (const float4*)cache_v, (float4*)keys, (float4*)vals);

  attn_mfma<<<B * H * (S / 64), blk, 0, stream>>>(q_buf, keys, vals, q_buf);

  gemm_bt<128, 128, 8, 8, 8><<<dim3(E / 128, (B * S) / 128), blk, 0, stream>>>(q_buf, Wo, out, B * S, E, E);
}

// Round 3
// 346.902 us; speedup vs baseline: 13.0970x; 2.9720x over previous
//
#include <hip/hip_runtime.h>
#include <cstddef>

#define B   2
#define S   1024
#define PP  1024          // start_pos
#define CTX 2048
#define E   2048
#define H   32
#define KVH 8
#define HD  64
#define GQ  4             // H / KVH
#define NQKV 3072         // E + 2*KVH*HD

typedef short s4v  __attribute__((ext_vector_type(4)));
typedef short s8v  __attribute__((ext_vector_type(8)));
typedef float f4v  __attribute__((ext_vector_type(4)));

__device__ __forceinline__ short f2bf(float f) {   // RNE f32 -> bf16
  union { float f; unsigned u; } v; v.f = f;
  unsigned r = v.u + 0x7fffu + ((v.u >> 16) & 1u);
  return (short)(r >> 16);
}

__device__ __forceinline__ void gl_lds16(const void* g, void* l) {
  // async 16B/lane global->LDS; LDS dest = wave-uniform base + lane*16
  __builtin_amdgcn_global_load_lds((const __attribute__((address_space(1))) unsigned*)g,
                                   (__attribute__((address_space(3))) unsigned*)l, 16, 0, 0);
}

// ---------------------------------------------------------------------------
// f32 -> bf16 convert, 8 elems/thread
// ---------------------------------------------------------------------------
__global__ __launch_bounds__(256) void f32_to_bf16(const float* __restrict__ s,
                                                   short* __restrict__ d, int n) {
  int i = (blockIdx.x * 256 + threadIdx.x) * 8;
  if (i >= n) return;
  float4 a = *(const float4*)&s[i];
  float4 b = *(const float4*)&s[i + 4];
  s8v o;
  o[0] = f2bf(a.x); o[1] = f2bf(a.y); o[2] = f2bf(a.z); o[3] = f2bf(a.w);
  o[4] = f2bf(b.x); o[5] = f2bf(b.y); o[6] = f2bf(b.z); o[7] = f2bf(b.w);
  *(s8v*)&d[i] = o;
}

// ---------------------------------------------------------------------------
// bf16 MFMA GEMM, C[M,N] (f32) = A[M,K] @ B[N,K]^T, m97 structure:
// 128x128 tile, BK=32, global_load_lds width16, 2x2 wave grid, 4x4 acc/wave.
// LDS staging XOR-swizzle: global chunk c8 lives at LDS slot c8^((row>>1)&3)
// -> frag ds_read_b128 rows spread 8 banks (2-way, free) instead of 8-way.
// ---------------------------------------------------------------------------
__global__ __launch_bounds__(256) void gemm_bf16(const short* __restrict__ A,
                                                 const short* __restrict__ Bw,
                                                 float* __restrict__ C,
                                                 int M, int N, int K) {
  __shared__ short As[4096];   // [128 rows][4 chunks][8] = 8 KB
  __shared__ short Bs[4096];
  const int tid  = threadIdx.x;
  const int wv   = tid >> 6, lane = tid & 63;
  const int wm   = wv & 1, wn = wv >> 1;
  const int n16  = lane & 15, g = lane >> 4;
  const int m0   = blockIdx.y * 128, n0 = blockIdx.x * 128;

  // staging coords (2 issues each for A and B)
  const int s0 = tid, s1 = 256 + tid;
  const int r0 = s0 >> 2, c0 = ((s0 & 3) ^ ((r0 >> 1) & 3)) * 8;
  const int r1 = s1 >> 2, c1 = ((s1 & 3) ^ ((r1 >> 1) & 3)) * 8;
  const short* pA0 = A + (size_t)(m0 + r0) * K + c0;
  const short* pA1 = A + (size_t)(m0 + r1) * K + c1;
  const short* pB0 = Bw + (size_t)(n0 + r0) * K + c0;
  const short* pB1 = Bw + (size_t)(n0 + r1) * K + c1;
  short* lA0 = As + (wv * 64) * 8;
  short* lA1 = As + (256 + wv * 64) * 8;
  short* lB0 = Bs + (wv * 64) * 8;
  short* lB1 = Bs + (256 + wv * 64) * 8;

  const int xv = (g ^ ((n16 >> 1) & 3)) * 8;  // frag-read swizzle (row>>1)&3 == (n16>>1)&3

  f4v acc[4][4] = {};
  for (int k0 = 0; k0 < K; k0 += 32) {
    __syncthreads();                      // previous tile's readers done
    gl_lds16(pA0, lA0); gl_lds16(pA1, lA1);
    gl_lds16(pB0, lB0); gl_lds16(pB1, lB1);
    pA0 += 32; pA1 += 32; pB0 += 32; pB1 += 32;
    __syncthreads();                      // compiler drains vmcnt before barrier

    s8v af[4], bf[4];
#pragma unroll
    for (int mt = 0; mt < 4; mt++)
      af[mt] = *(const s8v*)&As[(wm * 64 + mt * 16 + n16) * 32 + xv];
#pragma unroll
    for (int nt = 0; nt < 4; nt++)
      bf[nt] = *(const s8v*)&Bs[(wn * 64 + nt * 16 + n16) * 32 + xv];
#pragma unroll
    for (int mt = 0; mt < 4; mt++)
#pragma unroll
      for (int nt = 0; nt < 4; nt++)
        acc[mt][nt] = __builtin_amdgcn_mfma_f32_16x16x32_bf16(af[mt], bf[nt], acc[mt][nt], 0, 0, 0);
  }

  // epilogue: D row = A-index (g*4+r), col = B-index (n16)
#pragma unroll
  for (int mt = 0; mt < 4; mt++)
#pragma unroll
    for (int nt = 0; nt < 4; nt++) {
      size_t base = (size_t)(m0 + wm * 64 + mt * 16 + g * 4) * N + n0 + wn * 64 + nt * 16 + n16;
#pragma unroll
      for (int r = 0; r < 4; r++)
        C[base + (size_t)r * N] = acc[mt][nt][r];
    }
}

// ---------------------------------------------------------------------------
// RoPE on q region of qkv buffer (row stride NQKV), in place.
// ---------------------------------------------------------------------------
__global__ __launch_bounds__(256) void rope_q(float* __restrict__ qkv,
                                              const float* __restrict__ cosb,
                                              const float* __restrict__ sinb) {
  int idx = blockIdx.x * 256 + threadIdx.x;   // B*S*H*32
  int d = idx & 31;
  int h = (idx >> 5) & (H - 1);
  int s = (idx >> 10) & (S - 1);
  int b = idx >> 20;
  size_t row = (size_t)b * S + s;
  float c = cosb[row * HD + d];
  float sn = sinb[row * HD + d];
  float* qp = qkv + row * NQKV + h * 64;
  float q1 = qp[d], q2 = qp[d + 32];
  qp[d] = q1 * c - q2 * sn;
  qp[d + 32] = q2 * c + q1 * sn;
}

// ---------------------------------------------------------------------------
// RoPE on k region + scatter k,v (bf16) into caches at pos PP+s.
// ---------------------------------------------------------------------------
__global__ __launch_bounds__(256) void rope_kv(const float* __restrict__ qkv,
                                               const float* __restrict__ cosb,
                                               const float* __restrict__ sinb,
                                               short* __restrict__ keys,
                                               short* __restrict__ vals) {
  int idx = blockIdx.x * 256 + threadIdx.x;   // B*S*KVH*32
  int d = idx & 31;
  int kv = (idx >> 5) & (KVH - 1);
  int s = (idx >> 8) & (S - 1);
  int b = idx >> 18;
  size_t row = (size_t)b * S + s;
  float c = cosb[row * HD + d];
  float sn = sinb[row * HD + d];
  const float* base = qkv + row * NQKV;
  float k1 = base[E + kv * 64 + d], k2 = base[E + kv * 64 + d + 32];
  float v1 = base[E + 512 + kv * 64 + d], v2 = base[E + 512 + kv * 64 + d + 32];
  size_t drow = (((size_t)b * KVH + kv) * CTX + PP + s) * HD;
  keys[drow + d]      = f2bf(k1 * c - k2 * sn);
  keys[drow + d + 32] = f2bf(k2 * c + k1 * sn);
  vals[drow + d]      = f2bf(v1);
  vals[drow + d + 32] = f2bf(v2);
}

// ---------------------------------------------------------------------------
// cache_k/cache_v f32 positions [0,PP) -> bf16 caches
// ---------------------------------------------------------------------------
__global__ __launch_bounds__(256) void copy_cache(const float* __restrict__ ck,
                                                  const float* __restrict__ cv,
                                                  short* __restrict__ keys,
                                                  short* __restrict__ vals) {
  int idx = blockIdx.x * 256 + threadIdx.x;   // B*KVH*PP*HD/8
  int bkv = idx >> 13;
  int rem = idx & 8191;
  size_t off = (size_t)bkv * (CTX * HD) + (size_t)rem * 8;
  float4 a = *(const float4*)&ck[off];
  float4 b = *(const float4*)&ck[off + 4];
  s8v o;
  o[0]=f2bf(a.x); o[1]=f2bf(a.y); o[2]=f2bf(a.z); o[3]=f2bf(a.w);
  o[4]=f2bf(b.x); o[5]=f2bf(b.y); o[6]=f2bf(b.z); o[7]=f2bf(b.w);
  *(s8v*)&keys[off] = o;
  a = *(const float4*)&cv[off];
  b = *(const float4*)&cv[off + 4];
  o[0]=f2bf(a.x); o[1]=f2bf(a.y); o[2]=f2bf(a.z); o[3]=f2bf(a.w);
  o[4]=f2bf(b.x); o[5]=f2bf(b.y); o[6]=f2bf(b.z); o[7]=f2bf(b.w);
  *(s8v*)&vals[off] = o;
}

// ---------------------------------------------------------------------------
// MFMA bf16 flash attention (as R1, but bf16 KV cache in / bf16 out,
// LDS stride 72 for 16B-aligned s8v access).
// ---------------------------------------------------------------------------
__global__ __launch_bounds__(256) void attn_mfma(const float* __restrict__ qkv,
                                                 const short* __restrict__ keys,
                                                 const short* __restrict__ vals,
                                                 short* __restrict__ attn) {
  __shared__ short Ks[64][72];     // K tile  [key][dim]
  __shared__ short VTs[64][72];    // V tile transposed [dim][key]
  __shared__ short Pb[4][16][72];  // per-wave P [query][key]

  const int sblk = 15 - (blockIdx.x & 15);     // long blocks first
  const int h    = (blockIdx.x >> 4) & (H - 1);
  const int b    = blockIdx.x >> 9;
  const int kv   = h >> 2;
  const int sq0  = sblk * 64;
  const int kend = PP + sq0 + 64;

  const int tid  = threadIdx.x;
  const int w    = tid >> 6;
  const int lane = tid & 63;
  const int n    = lane & 15;
  const int g    = lane >> 4;

  const short* kbase = keys + ((size_t)b * KVH + kv) * CTX * HD;
  const short* vbase = vals + ((size_t)b * KVH + kv) * CTX * HD;

  // Q fragments (fp32 from qkv buffer, fold 1/sqrt(HD))
  union { s4v h4[2]; s8v v; } qlo, qhi;
  {
    const float* qrow = qkv + ((size_t)b * S + sq0 + w * 16 + n) * NQKV + h * 64;
    float4 f0 = *(const float4*)&qrow[g * 8];
    float4 f1 = *(const float4*)&qrow[g * 8 + 4];
    float4 f2 = *(const float4*)&qrow[32 + g * 8];
    float4 f3 = *(const float4*)&qrow[32 + g * 8 + 4];
    s4v a, c;
    a[0]=f2bf(f0.x*0.125f); a[1]=f2bf(f0.y*0.125f); a[2]=f2bf(f0.z*0.125f); a[3]=f2bf(f0.w*0.125f);
    qlo.h4[0]=a;
    a[0]=f2bf(f1.x*0.125f); a[1]=f2bf(f1.y*0.125f); a[2]=f2bf(f1.z*0.125f); a[3]=f2bf(f1.w*0.125f);
    qlo.h4[1]=a;
    c[0]=f2bf(f2.x*0.125f); c[1]=f2bf(f2.y*0.125f); c[2]=f2bf(f2.z*0.125f); c[3]=f2bf(f2.w*0.125f);
    qhi.h4[0]=c;
    c[0]=f2bf(f3.x*0.125f); c[1]=f2bf(f3.y*0.125f); c[2]=f2bf(f3.z*0.125f); c[3]=f2bf(f3.w*0.125f);
    qhi.h4[1]=c;
  }

  f4v O0 = {0,0,0,0}, O1 = {0,0,0,0}, O2 = {0,0,0,0}, O3 = {0,0,0,0};
  float m = -3e38f, l = 0.f;
  const int qp     = PP + sq0 + w * 16 + n;
  const int qmin_w = PP + sq0 + w * 16;

  for (int k0 = 0; k0 < kend; k0 += 64) {
    __syncthreads();
    { // stage K tile: 16 bf16/thread
      int row = tid >> 2, c16 = (tid & 3) * 16;
      const short* kr = kbase + (size_t)(k0 + row) * HD + c16;
      s8v a = *(const s8v*)kr;
      s8v bb = *(const s8v*)(kr + 8);
      *(s8v*)&Ks[row][c16] = a;
      *(s8v*)&Ks[row][c16 + 8] = bb;
      // stage V^T: 4x4 transpose
      int dq = tid & 15, kb = tid >> 4;
      s4v vv[4];
#pragma unroll
      for (int i = 0; i < 4; i++)
        vv[i] = *(const s4v*)&vbase[(size_t)(k0 + kb * 4 + i) * HD + dq * 4];
#pragma unroll
      for (int j = 0; j < 4; j++) {
        s4v p; p[0]=vv[0][j]; p[1]=vv[1][j]; p[2]=vv[2][j]; p[3]=vv[3][j];
        *(s4v*)&VTs[dq * 4 + j][kb * 4] = p;
      }
    }
    __syncthreads();

    // S^T = K_tile @ Q^T
    f4v sc[4];
#pragma unroll
    for (int st = 0; st < 4; st++) {
      s8v alo = *(const s8v*)&Ks[st * 16 + n][g * 8];
      s8v ahi = *(const s8v*)&Ks[st * 16 + n][32 + g * 8];
      f4v z = {0.f, 0.f, 0.f, 0.f};
      z = __builtin_amdgcn_mfma_f32_16x16x32_bf16(alo, qlo.v, z, 0, 0, 0);
      sc[st] = __builtin_amdgcn_mfma_f32_16x16x32_bf16(ahi, qhi.v, sc[st] = z, 0, 0, 0);
    }

    // causal mask near diagonal
    if (k0 + 63 > qmin_w) {
#pragma unroll
      for (int st = 0; st < 4; st++)
#pragma unroll
        for (int r = 0; r < 4; r++) {
          int kpos = k0 + st * 16 + g * 4 + r;
          if (kpos > qp) sc[st][r] = -3e38f;
        }
    }

    // online softmax (per query col n)
    float ml = sc[0][0];
#pragma unroll
    for (int st = 0; st < 4; st++)
#pragma unroll
      for (int r = 0; r < 4; r++) ml = fmaxf(ml, sc[st][r]);
    ml = fmaxf(ml, __shfl_xor(ml, 16));
    ml = fmaxf(ml, __shfl_xor(ml, 32));
    float mn = fmaxf(m, ml);
    float alpha = __expf(m - mn);
    m = mn;
    float ls = 0.f;
#pragma unroll
    for (int st = 0; st < 4; st++) {
      s4v pw;
#pragma unroll
      for (int r = 0; r < 4; r++) {
        float e = __expf(sc[st][r] - m);
        ls += e;
        pw[r] = f2bf(e);
      }
      *(s4v*)&Pb[w][n][st * 16 + g * 4] = pw;
    }
    ls += __shfl_xor(ls, 16);
    ls += __shfl_xor(ls, 32);
    l = l * alpha + ls;

#pragma unroll
    for (int r = 0; r < 4; r++) {
      float ar = __shfl(alpha, g * 4 + r, 64);
      O0[r] *= ar; O1[r] *= ar; O2[r] *= ar; O3[r] *= ar;
    }

    // O += P @ V
#pragma unroll
    for (int kh = 0; kh < 2; kh++) {
      s8v pa = *(const s8v*)&Pb[w][n][kh * 32 + g * 8];
      s8v vb;
      vb = *(const s8v*)&VTs[0 * 16 + n][kh * 32 + g * 8];
      O0 = __builtin_amdgcn_mfma_f32_16x16x32_bf16(pa, vb, O0, 0, 0, 0);
      vb = *(const s8v*)&VTs[1 * 16 + n][kh * 32 + g * 8];
      O1 = __builtin_amdgcn_mfma_f32_16x16x32_bf16(pa, vb, O1, 0, 0, 0);
      vb = *(const s8v*)&VTs[2 * 16 + n][kh * 32 + g * 8];
      O2 = __builtin_amdgcn_mfma_f32_16x16x32_bf16(pa, vb, O2, 0, 0, 0);
      vb = *(const s8v*)&VTs[3 * 16 + n][kh * 32 + g * 8];
      O3 = __builtin_amdgcn_mfma_f32_16x16x32_bf16(pa, vb, O3, 0, 0, 0);
    }
  }

  // epilogue: bf16 out, layout (b, s, h*64+d)
#pragma unroll
  for (int r = 0; r < 4; r++) {
    float rl = 1.f / __shfl(l, g * 4 + r, 64);
    short* orow = attn + ((size_t)b * S + sq0 + w * 16 + g * 4 + r) * E + h * 64 + n;
    orow[0]  = f2bf(O0[r] * rl);
    orow[16] = f2bf(O1[r] * rl);
    orow[32] = f2bf(O2[r] * rl);
    orow[48] = f2bf(O3[r] * rl);
  }
}

// ---------------------------------------------------------------------------
extern "C" void kernel_launch(void* const* d_in, const int* in_sizes, int n_in,
                              void* d_out, int out_size, void* d_ws, size_t ws_size,
                              hipStream_t stream) {
  const float* x       = (const float*)d_in[0];
  const float* cosb    = (const float*)d_in[1];
  const float* sinb    = (const float*)d_in[2];
  const float* cache_k = (const float*)d_in[4];
  const float* cache_v = (const float*)d_in[5];
  const float* Wq      = (const float*)d_in[6];
  const float* Wk      = (const float*)d_in[7];
  const float* Wv      = (const float*)d_in[8];
  const float* Wo      = (const float*)d_in[9];
  float* out = (float*)d_out;

  short* xb    = (short*)d_ws;                 // 4194304 bf16
  short* wqkv  = xb + 4194304;                 // 6291456 bf16 ([Wq;Wk;Wv], [3072][2048])
  short* wob   = wqkv + 6291456;               // 4194304 bf16
  short* keysb = wob + 4194304;                // 2097152 bf16
  short* valsb = keysb + 2097152;              // 2097152 bf16
  short* aout  = valsb + 2097152;              // 4194304 bf16 (attn out, (B,S,E))
  float* qkv   = (float*)(aout + 4194304);     // 6291456 f32  ((B,S,3072)); total ~68 MB

  dim3 blk(256);

  // converts
  f32_to_bf16<<<2048, blk, 0, stream>>>(x,  xb,   4194304);
  f32_to_bf16<<<2048, blk, 0, stream>>>(Wq, wqkv, 4194304);
  f32_to_bf16<<<512,  blk, 0, stream>>>(Wk, wqkv + 4194304, 1048576);
  f32_to_bf16<<<512,  blk, 0, stream>>>(Wv, wqkv + 5242880, 1048576);
  f32_to_bf16<<<2048, blk, 0, stream>>>(Wo, wob, 4194304);

  // fused QKV projection: [2048,2048] @ [3072,2048]^T
  gemm_bf16<<<dim3(NQKV / 128, (B * S) / 128), blk, 0, stream>>>(xb, wqkv, qkv, B * S, NQKV, E);

  // RoPE + KV cache assembly (bf16 caches)
  rope_q<<<(B * S * H * 32) / 256, blk, 0, stream>>>(qkv, cosb, sinb);
  rope_kv<<<(B * S * KVH * 32) / 256, blk, 0, stream>>>(qkv, cosb, sinb, keysb, valsb);
  copy_cache<<<(B * KVH * PP * HD / 8) / 256, blk, 0, stream>>>(cache_k, cache_v, keysb, valsb);

  // attention -> bf16 (B,S,E)
  attn_mfma<<<B * H * (S / 64), blk, 0, stream>>>(qkv, keysb, valsb, aout);

  // output projection: [2048,2048] @ [2048,2048]^T -> f32 out
  gemm_bf16<<<dim3(E / 128, (B * S) / 128), blk, 0, stream>>>(aout, wob, out, B * S, E, E);
}